// Round 11
// baseline (285.568 us; speedup 1.0000x reference)
//
#include <hip/hip_runtime.h>
#include <math.h>

// ---------- problem constants ----------
constexpr int NN1 = 65536, NN2 = 8192, NN3 = 1024;
constexpr int E0 = 655360, E1 = 81920, E2 = 10240;
constexpr int ETOT = E0 + E1 + E2;           // 747520
constexpr int NTOT = NN1 + NN2 + NN3;        // 74752

static inline int cdiv(int a, int b) { return (a + b - 1) / b; }

typedef __bf16 bf16x8_t __attribute__((ext_vector_type(8)));
typedef float f32x4_t __attribute__((ext_vector_type(4)));

__device__ __forceinline__ unsigned short f2bf(float f) {
    union { float f; unsigned int u; } v; v.f = f;
    unsigned int r = v.u + 0x7fffu + ((v.u >> 16) & 1u);
    return (unsigned short)(r >> 16);
}
__device__ __forceinline__ float bf2f(unsigned short h) {
    union { unsigned int u; float f; } v; v.u = ((unsigned int)h) << 16;
    return v.f;
}

// ---------- fused CSR count + weight prep (4-way sharded atomics) ----------
constexpr int CB = (ETOT + 255) / 256;   // 2920
__global__ void count_prep(const int* __restrict__ dst0, const int* __restrict__ dst1,
                           const int* __restrict__ dst2, int* __restrict__ cnt4,
                           const float* __restrict__ Wl0, const float* __restrict__ Wr0,
                           unsigned short* __restrict__ Wt0a, unsigned short* __restrict__ Wt0b,
                           const float* __restrict__ Wl1, const float* __restrict__ Wr1,
                           unsigned short* __restrict__ Wt1a, unsigned short* __restrict__ Wt1b) {
    int b = blockIdx.x, t = threadIdx.x;
    if (b < CB) {
        int* cnt = cnt4 + (size_t)(b & 3) * NTOT;   // shard by block (deterministic)
        int i = b * 256 + t;
        if (i < E0) atomicAdd(&cnt[dst0[i]], 1);
        else if (i < E0 + E1) atomicAdd(&cnt[NN1 + dst1[i - E0]], 1);
        else if (i < ETOT) atomicAdd(&cnt[NN1 + NN2 + dst2[i - E0 - E1]], 1);
        return;
    }
    b -= CB;
    if (b < 128) {
        int idx = b * 256 + t; int n = idx >> 7, k = idx & 127;
        Wt0a[idx] = f2bf(k < 100 ? Wl0[k * 256 + n] : 0.f);
    } else if (b < 256) {
        int idx = (b - 128) * 256 + t; int n = idx >> 7, k = idx & 127;
        Wt0b[idx] = f2bf(k < 100 ? Wr0[k * 256 + n] : 0.f);
    } else if (b < 512) {
        int idx = (b - 256) * 256 + t; int n = idx >> 8, k = idx & 255;
        Wt1a[idx] = f2bf(Wl1[k * 256 + n]);
    } else {
        int idx = (b - 512) * 256 + t; int n = idx >> 8, k = idx & 255;
        Wt1b[idx] = f2bf(Wr1[k * 256 + n]);
    }
}

__global__ __launch_bounds__(1024) void scan1(const int* __restrict__ cnt4, int n,
                                              int* __restrict__ ofs, int* __restrict__ sums) {
    __shared__ int s[1024];
    int i = blockIdx.x * 1024 + threadIdx.x;
    int v = 0;
    if (i < n)
        v = cnt4[i] + cnt4[NTOT + i] + cnt4[2 * NTOT + i] + cnt4[3 * NTOT + i];
    s[threadIdx.x] = v;
    __syncthreads();
    for (int off = 1; off < 1024; off <<= 1) {
        int t = (threadIdx.x >= off) ? s[threadIdx.x - off] : 0;
        __syncthreads();
        s[threadIdx.x] += t;
        __syncthreads();
    }
    if (i < n) ofs[i] = s[threadIdx.x] - v;
    if (threadIdx.x == 1023) sums[blockIdx.x] = s[1023];
}

// add chunk prefix; emit per-shard cursor bases (disjoint slot ranges per node)
__global__ void scan3(const int* __restrict__ sums, int n,
                      int* __restrict__ ofs, const int* __restrict__ cnt4,
                      int* __restrict__ cursor4) {
    __shared__ int pref_s;
    int c = (blockIdx.x * 256) >> 10;
    if (threadIdx.x < 64) {
        int v = 0;
        for (int j = threadIdx.x; j < c; j += 64) v += sums[j];
        for (int o = 32; o; o >>= 1) v += __shfl_down(v, o);
        if (threadIdx.x == 0) pref_s = v;
    }
    __syncthreads();
    int i = blockIdx.x * 256 + threadIdx.x;
    if (i < n) {
        int base = ofs[i] + pref_s;
        ofs[i] = base;
        int run = base;
#pragma unroll
        for (int s = 0; s < 4; ++s) {
            cursor4[(size_t)s * NTOT + i] = run;
            run += cnt4[(size_t)s * NTOT + i];
        }
    }
    if (blockIdx.x == 0 && threadIdx.x == 0) ofs[n] = ETOT;
}

__global__ void scatter_all(const int* __restrict__ src0, const int* __restrict__ dst0,
                            const int* __restrict__ src1, const int* __restrict__ dst1,
                            const int* __restrict__ src2, const int* __restrict__ dst2,
                            int* __restrict__ cursor4, int* __restrict__ perm) {
    int* cursor = cursor4 + (size_t)(blockIdx.x & 3) * NTOT;   // same shard fn as count
    int i = blockIdx.x * 256 + threadIdx.x;
    if (i < E0) {
        int p = atomicAdd(&cursor[dst0[i]], 1);
        perm[p] = src0[i];
    } else if (i < E0 + E1) {
        int j = i - E0;
        int p = atomicAdd(&cursor[NN1 + dst1[j]], 1);
        perm[p] = src1[j];
    } else if (i < ETOT) {
        int j = i - E0 - E1;
        int p = atomicAdd(&cursor[NN1 + NN2 + dst2[j]], 1);
        perm[p] = src2[j];
    }
}

// ---------- fused layer 0: BM=64 (8 rows/wave), pair-pipelined gather + dual MFMA + ReLU ----------
__global__ __launch_bounds__(512) void fused_l0(const float* __restrict__ x,
                                                const int* __restrict__ perm,
                                                const int* __restrict__ ofs,
                                                const unsigned short* __restrict__ Wt0a,
                                                const unsigned short* __restrict__ Wt0b,
                                                const float* __restrict__ bias,
                                                unsigned short* __restrict__ h1) {
    __shared__ unsigned short As[64][136];
    __shared__ unsigned short Bs[256][40];
    int tid = threadIdx.x;
    int lane = tid & 63, wid = tid >> 6;
    int bm = blockIdx.x * 64;

    // ---- gather phase (pair-pipelined, 8 rows per wave) ----
    {
        int g = lane >> 5, l5 = lane & 31;
        bool act = l5 < 25;
        int node0 = bm + wid * 8;
        int myofs = (lane < 9) ? ofs[node0 + lane] : 0;

        int s0a = __shfl(myofs, 0);
        int s0b = __shfl(myofs, 1);
        int s1b = __shfl(myofs, 2);
        int dega = s0b - s0a, degb = s1b - s0b;
        int dca = min(dega, 64), dcb = min(degb, 64);
        int pea = (lane < dca) ? perm[s0a + lane] : 0;
        int peb = (lane < dcb) ? perm[s0b + lane] : 0;

        for (int r = 0; r < 8; r += 2) {
            int s0a_n = 0, s0b_n = 0, dega_n = 0, degb_n = 0, dca_n = 0, dcb_n = 0;
            int pea_n = 0, peb_n = 0;
            if (r + 2 < 8) {
                s0a_n = __shfl(myofs, r + 2);
                s0b_n = __shfl(myofs, r + 3);
                int s1b_n = __shfl(myofs, r + 4);
                dega_n = s0b_n - s0a_n; degb_n = s1b_n - s0b_n;
                dca_n = min(dega_n, 64); dcb_n = min(degb_n, 64);
                pea_n = (lane < dca_n) ? perm[s0a_n + lane] : 0;
                peb_n = (lane < dcb_n) ? perm[s0b_n + lane] : 0;
            }
            f32x4_t A0 = {0.f, 0.f, 0.f, 0.f}, A1 = A0, A2 = A0, A3 = A0;
            f32x4_t B0 = A0, B1 = A0, B2 = A0, B3 = A0;
            int mx = max(dca, dcb);
            for (int b = 0; b < mx; b += 8) {
                int e0 = b + g, e1 = b + 2 + g, e2 = b + 4 + g, e3 = b + 6 + g;
                int pa0 = __shfl(pea, e0), pa1 = __shfl(pea, e1);
                int pa2 = __shfl(pea, e2), pa3 = __shfl(pea, e3);
                int pb0 = __shfl(peb, e0), pb1 = __shfl(peb, e1);
                int pb2 = __shfl(peb, e2), pb3 = __shfl(peb, e3);
                f32x4_t z = {0.f, 0.f, 0.f, 0.f};
                f32x4_t va0 = z, va1 = z, va2 = z, va3 = z;
                f32x4_t vb0 = z, vb1 = z, vb2 = z, vb3 = z;
                if (act && e0 < dca) va0 = *reinterpret_cast<const f32x4_t*>(x + (size_t)pa0 * 100 + l5 * 4);
                if (act && e1 < dca) va1 = *reinterpret_cast<const f32x4_t*>(x + (size_t)pa1 * 100 + l5 * 4);
                if (act && e2 < dca) va2 = *reinterpret_cast<const f32x4_t*>(x + (size_t)pa2 * 100 + l5 * 4);
                if (act && e3 < dca) va3 = *reinterpret_cast<const f32x4_t*>(x + (size_t)pa3 * 100 + l5 * 4);
                if (act && e0 < dcb) vb0 = *reinterpret_cast<const f32x4_t*>(x + (size_t)pb0 * 100 + l5 * 4);
                if (act && e1 < dcb) vb1 = *reinterpret_cast<const f32x4_t*>(x + (size_t)pb1 * 100 + l5 * 4);
                if (act && e2 < dcb) vb2 = *reinterpret_cast<const f32x4_t*>(x + (size_t)pb2 * 100 + l5 * 4);
                if (act && e3 < dcb) vb3 = *reinterpret_cast<const f32x4_t*>(x + (size_t)pb3 * 100 + l5 * 4);
                A0 += va0; A1 += va1; A2 += va2; A3 += va3;
                B0 += vb0; B1 += vb1; B2 += vb2; B3 += vb3;
            }
            for (int e = s0a + 64; e < s0a + dega; e += 2) {
                int idx = e + g;
                if (act && idx < s0a + dega)
                    A0 += *reinterpret_cast<const f32x4_t*>(x + (size_t)perm[idx] * 100 + l5 * 4);
            }
            for (int e = s0b + 64; e < s0b + degb; e += 2) {
                int idx = e + g;
                if (act && idx < s0b + degb)
                    B0 += *reinterpret_cast<const f32x4_t*>(x + (size_t)perm[idx] * 100 + l5 * 4);
            }
            f32x4_t a = (A0 + A1) + (A2 + A3);
            f32x4_t bb = (B0 + B1) + (B2 + B3);
#pragma unroll
            for (int c = 0; c < 4; c++) {
                a[c] += __shfl_xor(a[c], 32);
                bb[c] += __shfl_xor(bb[c], 32);
            }
            float inva = 1.0f / fmaxf((float)dega, 1.0f);
            float invb = 1.0f / fmaxf((float)degb, 1.0f);
            int rowa = wid * 8 + r, rowb = rowa + 1;
            if (lane < 25) {
                ushort4 oa, ob;
                oa.x = f2bf(a[0] * inva); oa.y = f2bf(a[1] * inva);
                oa.z = f2bf(a[2] * inva); oa.w = f2bf(a[3] * inva);
                ob.x = f2bf(bb[0] * invb); ob.y = f2bf(bb[1] * invb);
                ob.z = f2bf(bb[2] * invb); ob.w = f2bf(bb[3] * invb);
                *reinterpret_cast<ushort4*>(&As[rowa][lane * 4]) = oa;
                *reinterpret_cast<ushort4*>(&As[rowb][lane * 4]) = ob;
            } else if (lane < 32) {
                ushort4 z4 = make_ushort4(0, 0, 0, 0);
                *reinterpret_cast<ushort4*>(&As[rowa][100 + (lane - 25) * 4]) = z4;
                *reinterpret_cast<ushort4*>(&As[rowb][100 + (lane - 25) * 4]) = z4;
            }
            s0a = s0a_n; s0b = s0b_n; dega = dega_n; degb = degb_n;
            dca = dca_n; dcb = dcb_n; pea = pea_n; peb = peb_n;
        }
    }

    f32x4_t acc[4][2];
#pragma unroll
    for (int i = 0; i < 4; i++)
#pragma unroll
        for (int j = 0; j < 2; j++)
#pragma unroll
            for (int r = 0; r < 4; r++) acc[i][j][r] = 0.f;

    int r0 = lane & 15, kg = lane >> 4;
    int wn = wid * 32;

    for (int pass = 0; pass < 2; ++pass) {
        const unsigned short* W = pass ? Wt0b : Wt0a;
        if (pass) {
            __syncthreads();
            for (int c = tid; c < 2048; c += 512) {
                int row = c >> 5, c4 = c & 31;
                if (c4 < 25) {
                    f32x4_t v = *reinterpret_cast<const f32x4_t*>(x + (size_t)(bm + row) * 100 + c4 * 4);
                    ushort4 o;
                    o.x = f2bf(v[0]); o.y = f2bf(v[1]); o.z = f2bf(v[2]); o.w = f2bf(v[3]);
                    *reinterpret_cast<ushort4*>(&As[row][c4 * 4]) = o;
                } else {
                    *reinterpret_cast<ushort4*>(&As[row][c4 * 4]) = make_ushort4(0, 0, 0, 0);
                }
            }
        }
#pragma unroll
        for (int ks = 0; ks < 4; ++ks) {
            __syncthreads();
            for (int c = tid; c < 1024; c += 512) {
                int n = c >> 2, k8 = (c & 3) << 3;
                *reinterpret_cast<int4*>(&Bs[n][k8]) =
                    *reinterpret_cast<const int4*>(&W[(size_t)n * 128 + ks * 32 + k8]);
            }
            __syncthreads();
            bf16x8_t af[4], bfv[2];
#pragma unroll
            for (int ni = 0; ni < 2; ni++)
                bfv[ni] = *reinterpret_cast<const bf16x8_t*>(&Bs[wn + ni * 16 + r0][kg * 8]);
#pragma unroll
            for (int mi = 0; mi < 4; mi++)
                af[mi] = *reinterpret_cast<const bf16x8_t*>(&As[mi * 16 + r0][ks * 32 + kg * 8]);
#pragma unroll
            for (int mi = 0; mi < 4; mi++)
#pragma unroll
                for (int ni = 0; ni < 2; ni++)
                    acc[mi][ni] = __builtin_amdgcn_mfma_f32_16x16x32_bf16(af[mi], bfv[ni], acc[mi][ni], 0, 0, 0);
        }
    }

    int cc = lane & 15, rr = (lane >> 4) * 4;
#pragma unroll
    for (int mi = 0; mi < 4; mi++) {
#pragma unroll
        for (int ni = 0; ni < 2; ni++) {
            int col = wn + ni * 16 + cc;
            float b = bias[col];
#pragma unroll
            for (int j = 0; j < 4; j++) {
                int row = bm + mi * 16 + rr + j;
                float v = fmaxf(acc[mi][ni][j] + b, 0.f);
                h1[(size_t)row * 256 + col] = f2bf(v);
            }
        }
    }
}

// ---------- fused layer 1: BM=32 (grid 256), pair-pipelined gather + dual MFMA -> h2 fp32 ----------
__global__ __launch_bounds__(512) void fused_l1(const unsigned short* __restrict__ h1,
                                                const int* __restrict__ perm,
                                                const int* __restrict__ ofs,
                                                const unsigned short* __restrict__ Wt1a,
                                                const unsigned short* __restrict__ Wt1b,
                                                const float* __restrict__ bias,
                                                float* __restrict__ h2) {
    __shared__ unsigned short As[32][264];
    int tid = threadIdx.x;
    int lane = tid & 63, wid = tid >> 6;
    int bm = blockIdx.x * 32;

    {
        int node0 = bm + wid * 4;
        int myofs = (lane < 5) ? ofs[node0 + lane] : 0;
        int s0a = __shfl(myofs, 0);
        int s0b = __shfl(myofs, 1);
        int s1b = __shfl(myofs, 2);
        int dega = s0b - s0a, degb = s1b - s0b;
        int dca = min(dega, 64), dcb = min(degb, 64);
        int pea = (lane < dca) ? perm[s0a + lane] : 0;
        int peb = (lane < dcb) ? perm[s0b + lane] : 0;

        for (int r = 0; r < 4; r += 2) {
            int s0a_n = 0, s0b_n = 0, dega_n = 0, degb_n = 0, dca_n = 0, dcb_n = 0;
            int pea_n = 0, peb_n = 0;
            if (r + 2 < 4) {
                s0a_n = __shfl(myofs, 2);
                s0b_n = __shfl(myofs, 3);
                int s1b_n = __shfl(myofs, 4);
                dega_n = s0b_n - s0a_n; degb_n = s1b_n - s0b_n;
                dca_n = min(dega_n, 64); dcb_n = min(degb_n, 64);
                pea_n = (lane < dca_n) ? perm[s0a_n + lane] : 0;
                peb_n = (lane < dcb_n) ? perm[s0b_n + lane] : 0;
            }
            float aca[4][4] = {}, acb[4][4] = {};
            int mx = max(dca, dcb);
            for (int b = 0; b < mx; b += 4) {
#pragma unroll
                for (int u = 0; u < 4; u++) {
                    int pau = __shfl(pea, b + u);
                    int pbu = __shfl(peb, b + u);
                    ushort4 va = make_ushort4(0, 0, 0, 0), vb = va;
                    if (b + u < dca) va = *reinterpret_cast<const ushort4*>(h1 + (size_t)pau * 256 + lane * 4);
                    if (b + u < dcb) vb = *reinterpret_cast<const ushort4*>(h1 + (size_t)pbu * 256 + lane * 4);
                    aca[u][0] += bf2f(va.x); aca[u][1] += bf2f(va.y);
                    aca[u][2] += bf2f(va.z); aca[u][3] += bf2f(va.w);
                    acb[u][0] += bf2f(vb.x); acb[u][1] += bf2f(vb.y);
                    acb[u][2] += bf2f(vb.z); acb[u][3] += bf2f(vb.w);
                }
            }
            for (int e = s0a + 64; e < s0a + dega; e++) {
                ushort4 v = *reinterpret_cast<const ushort4*>(h1 + (size_t)perm[e] * 256 + lane * 4);
                aca[0][0] += bf2f(v.x); aca[0][1] += bf2f(v.y);
                aca[0][2] += bf2f(v.z); aca[0][3] += bf2f(v.w);
            }
            for (int e = s0b + 64; e < s0b + degb; e++) {
                ushort4 v = *reinterpret_cast<const ushort4*>(h1 + (size_t)perm[e] * 256 + lane * 4);
                acb[0][0] += bf2f(v.x); acb[0][1] += bf2f(v.y);
                acb[0][2] += bf2f(v.z); acb[0][3] += bf2f(v.w);
            }
            float inva = 1.0f / fmaxf((float)dega, 1.0f);
            float invb = 1.0f / fmaxf((float)degb, 1.0f);
            ushort4 oa, ob;
            oa.x = f2bf((aca[0][0] + aca[1][0] + aca[2][0] + aca[3][0]) * inva);
            oa.y = f2bf((aca[0][1] + aca[1][1] + aca[2][1] + aca[3][1]) * inva);
            oa.z = f2bf((aca[0][2] + aca[1][2] + aca[2][2] + aca[3][2]) * inva);
            oa.w = f2bf((aca[0][3] + aca[1][3] + aca[2][3] + aca[3][3]) * inva);
            ob.x = f2bf((acb[0][0] + acb[1][0] + acb[2][0] + acb[3][0]) * invb);
            ob.y = f2bf((acb[0][1] + acb[1][1] + acb[2][1] + acb[3][1]) * invb);
            ob.z = f2bf((acb[0][2] + acb[1][2] + acb[2][2] + acb[3][2]) * invb);
            ob.w = f2bf((acb[0][3] + acb[1][3] + acb[2][3] + acb[3][3]) * invb);
            *reinterpret_cast<ushort4*>(&As[wid * 4 + r][lane * 4]) = oa;
            *reinterpret_cast<ushort4*>(&As[wid * 4 + r + 1][lane * 4]) = ob;
            s0a = s0a_n; s0b = s0b_n; dega = dega_n; degb = degb_n;
            dca = dca_n; dcb = dcb_n; pea = pea_n; peb = peb_n;
        }
    }

    f32x4_t acc[2][2];
#pragma unroll
    for (int i = 0; i < 2; i++)
#pragma unroll
        for (int j = 0; j < 2; j++)
#pragma unroll
            for (int r = 0; r < 4; r++) acc[i][j][r] = 0.f;

    int r0 = lane & 15, kg = lane >> 4;
    int wn = wid * 32;

    for (int pass = 0; pass < 2; ++pass) {
        const unsigned short* W = pass ? Wt1b : Wt1a;
        if (pass) {
            __syncthreads();
            for (int c = tid; c < 1024; c += 512) {
                int row = c >> 5, k8 = (c & 31) << 3;
                *reinterpret_cast<int4*>(&As[row][k8]) =
                    *reinterpret_cast<const int4*>(&h1[(size_t)(bm + row) * 256 + k8]);
            }
        }
        __syncthreads();
#pragma unroll
        for (int ks = 0; ks < 8; ++ks) {
            bf16x8_t af[2], bfv[2];
#pragma unroll
            for (int ni = 0; ni < 2; ni++)
                bfv[ni] = *reinterpret_cast<const bf16x8_t*>(&W[(size_t)(wn + ni * 16 + r0) * 256 + ks * 32 + kg * 8]);
#pragma unroll
            for (int mi = 0; mi < 2; mi++)
                af[mi] = *reinterpret_cast<const bf16x8_t*>(&As[mi * 16 + r0][ks * 32 + kg * 8]);
#pragma unroll
            for (int mi = 0; mi < 2; mi++)
#pragma unroll
                for (int ni = 0; ni < 2; ni++)
                    acc[mi][ni] = __builtin_amdgcn_mfma_f32_16x16x32_bf16(af[mi], bfv[ni], acc[mi][ni], 0, 0, 0);
        }
    }

    int cc = lane & 15, rr = (lane >> 4) * 4;
#pragma unroll
    for (int mi = 0; mi < 2; mi++) {
#pragma unroll
        for (int ni = 0; ni < 2; ni++) {
            int col = wn + ni * 16 + cc;
            float b = bias[col];
#pragma unroll
            for (int j = 0; j < 4; j++) {
                int row = bm + mi * 16 + rr + j;
                h2[(size_t)row * 256 + col] = fmaxf(acc[mi][ni][j] + b, 0.f);
            }
        }
    }
}

// ---------- layer-2 aggregate ----------
__global__ void agg_vec4_256(const float* __restrict__ x, const int* __restrict__ perm,
                             const int* __restrict__ ofs, float* __restrict__ agg, int nrows) {
    int wave = (blockIdx.x * blockDim.x + threadIdx.x) >> 6;
    int lane = threadIdx.x & 63;
    if (wave >= nrows) return;
    int s0 = ofs[wave], s1 = ofs[wave + 1];
    float4 acc = make_float4(0.f, 0.f, 0.f, 0.f);
    for (int e = s0; e < s1; e++) {
        const float4* xr = (const float4*)(x + (size_t)perm[e] * 256);
        float4 v = xr[lane];
        acc.x += v.x; acc.y += v.y; acc.z += v.z; acc.w += v.w;
    }
    float inv = 1.0f / fmaxf((float)(s1 - s0), 1.0f);
    acc.x *= inv; acc.y *= inv; acc.z *= inv; acc.w *= inv;
    ((float4*)(agg + (size_t)wave * 256))[lane] = acc;
}

// ---------- layer-2: fp32 dual GEMM with fused log_softmax ----------
__global__ __launch_bounds__(256) void gemm2_fused(const float* __restrict__ A1, const float* __restrict__ W1, int K1,
                                                   const float* __restrict__ A2, const float* __restrict__ W2, int K2,
                                                   const float* __restrict__ bias, float* __restrict__ out,
                                                   int M, int N) {
    __shared__ float As[16][65];
    __shared__ float Bs[16][64];
    int tid = threadIdx.x;
    int tx = tid & 15, ty = tid >> 4;
    int bm = blockIdx.y * 64;
    float acc[4][4] = {};
    for (int pass = 0; pass < 2; ++pass) {
        const float* A = pass ? A2 : A1;
        const float* W = pass ? W2 : W1;
        int K = pass ? K2 : K1;
        for (int k0 = 0; k0 < K; k0 += 16) {
#pragma unroll
            for (int i = 0; i < 4; i++) {
                int L = i * 256 + tid;
                int m = L >> 4, k = L & 15;
                int gm = bm + m, gk = k0 + k;
                float v = 0.f;
                if (gm < M && gk < K) v = A[(size_t)gm * K + gk];
                As[k][m] = v;
            }
#pragma unroll
            for (int i = 0; i < 4; i++) {
                int L = i * 256 + tid;
                int n = L & 63, k = L >> 6;
                int gk = k0 + k;
                float v = 0.f;
                if (gk < K && n < N) v = W[(size_t)gk * N + n];
                Bs[k][n] = v;
            }
            __syncthreads();
#pragma unroll
            for (int k = 0; k < 16; k++) {
                float a[4], b[4];
#pragma unroll
                for (int i = 0; i < 4; i++) a[i] = As[k][ty * 4 + i];
#pragma unroll
                for (int j = 0; j < 4; j++) b[j] = Bs[k][tx * 4 + j];
#pragma unroll
                for (int i = 0; i < 4; i++)
#pragma unroll
                    for (int j = 0; j < 4; j++) acc[i][j] += a[i] * b[j];
            }
            __syncthreads();
        }
    }
#pragma unroll
    for (int i = 0; i < 4; i++) {
        int gm = bm + ty * 4 + i;
        float vals[4];
        float vmax = -1e30f;
#pragma unroll
        for (int j = 0; j < 4; j++) {
            int gn = tx * 4 + j;
            vals[j] = (gn < N) ? acc[i][j] + bias[gn] : -1e30f;
            vmax = fmaxf(vmax, vals[j]);
        }
#pragma unroll
        for (int o = 1; o < 16; o <<= 1) vmax = fmaxf(vmax, __shfl_xor(vmax, o));
        float se = 0.f;
#pragma unroll
        for (int j = 0; j < 4; j++) {
            int gn = tx * 4 + j;
            if (gn < N) se += expf(vals[j] - vmax);
        }
#pragma unroll
        for (int o = 1; o < 16; o <<= 1) se += __shfl_xor(se, o);
        float ls = logf(se);
#pragma unroll
        for (int j = 0; j < 4; j++) {
            int gn = tx * 4 + j;
            if (gn < N && gm < M) out[(size_t)gm * N + gn] = vals[j] - vmax - ls;
        }
    }
}

extern "C" void kernel_launch(void* const* d_in, const int* in_sizes, int n_in,
                              void* d_out, int out_size, void* d_ws, size_t ws_size,
                              hipStream_t stream) {
    const float* x   = (const float*)d_in[0];
    const int* src0  = (const int*)d_in[1];
    const int* dst0  = (const int*)d_in[2];
    const int* src1  = (const int*)d_in[3];
    const int* dst1  = (const int*)d_in[4];
    const int* src2  = (const int*)d_in[5];
    const int* dst2  = (const int*)d_in[6];
    const float* Wl0 = (const float*)d_in[7];
    const float* bl0 = (const float*)d_in[8];
    const float* Wr0 = (const float*)d_in[9];
    const float* Wl1 = (const float*)d_in[10];
    const float* bl1 = (const float*)d_in[11];
    const float* Wr1 = (const float*)d_in[12];
    const float* Wl2 = (const float*)d_in[13];
    const float* bl2 = (const float*)d_in[14];
    const float* Wr2 = (const float*)d_in[15];
    float* out = (float*)d_out;

    // ---- workspace layout ----
    char* p = (char*)d_ws;
    auto alloc = [&](size_t bytes) { char* r = p; p += (bytes + 255) & ~(size_t)255; return r; };
    unsigned short* h1   = (unsigned short*)alloc((size_t)NN1 * 256 * 2);
    float* h2    = (float*)alloc((size_t)NN2 * 256 * 4);
    float* agg2  = (float*)alloc((size_t)NN3 * 256 * 4);
    unsigned short* Wt0a = (unsigned short*)alloc(256 * 128 * 2);
    unsigned short* Wt0b = (unsigned short*)alloc(256 * 128 * 2);
    unsigned short* Wt1a = (unsigned short*)alloc(256 * 256 * 2);
    unsigned short* Wt1b = (unsigned short*)alloc(256 * 256 * 2);
    int* cnt4    = (int*)alloc((size_t)4 * NTOT * 4);
    int* ofs     = (int*)alloc((size_t)(NTOT + 1) * 4);
    int* cursor4 = (int*)alloc((size_t)4 * NTOT * 4);
    int* sums    = (int*)alloc(128 * 4);
    int* perm    = (int*)alloc((size_t)ETOT * 4);

    // ---- CSR build (4-way sharded atomics) + weight prep ----
    hipMemsetAsync(cnt4, 0, (size_t)4 * NTOT * 4, stream);
    count_prep<<<CB + 768, 256, 0, stream>>>(dst0, dst1, dst2, cnt4,
                                             Wl0, Wr0, Wt0a, Wt0b, Wl1, Wr1, Wt1a, Wt1b);
    int nb = cdiv(NTOT, 1024);   // 73
    scan1<<<nb, 1024, 0, stream>>>(cnt4, NTOT, ofs, sums);
    scan3<<<cdiv(NTOT, 256), 256, 0, stream>>>(sums, NTOT, ofs, cnt4, cursor4);
    scatter_all<<<cdiv(ETOT, 256), 256, 0, stream>>>(src0, dst0, src1, dst1, src2, dst2, cursor4, perm);

    // ---- layer 0 ----
    fused_l0<<<NN1 / 64, 512, 0, stream>>>(x, perm, ofs, Wt0a, Wt0b, bl0, h1);

    // ---- layer 1 ----
    fused_l1<<<NN2 / 32, 512, 0, stream>>>(h1, perm, ofs + NN1, Wt1a, Wt1b, bl1, h2);

    // ---- layer 2 ----
    agg_vec4_256<<<cdiv(NN3 * 64, 256), 256, 0, stream>>>(h2, perm, ofs + NN1 + NN2, agg2, NN3);
    {
        dim3 grid(1, NN3 / 64);
        gemm2_fused<<<grid, 256, 0, stream>>>(agg2, Wl2, 256, h2, Wr2, 256, bl2, out, NN3, 47);
    }
}

// Round 12
// 276.629 us; speedup vs baseline: 1.0323x; 1.0323x over previous
//
#include <hip/hip_runtime.h>
#include <math.h>

// ---------- problem constants ----------
constexpr int NN1 = 65536, NN2 = 8192, NN3 = 1024;
constexpr int E0 = 655360, E1 = 81920, E2 = 10240;
constexpr int ETOT = E0 + E1 + E2;           // 747520
constexpr int NTOT = NN1 + NN2 + NN3;        // 74752

static inline int cdiv(int a, int b) { return (a + b - 1) / b; }

typedef __bf16 bf16x8_t __attribute__((ext_vector_type(8)));
typedef float f32x4_t __attribute__((ext_vector_type(4)));

__device__ __forceinline__ unsigned short f2bf(float f) {
    union { float f; unsigned int u; } v; v.f = f;
    unsigned int r = v.u + 0x7fffu + ((v.u >> 16) & 1u);
    return (unsigned short)(r >> 16);
}
__device__ __forceinline__ float bf2f(unsigned short h) {
    union { unsigned int u; float f; } v; v.u = ((unsigned int)h) << 16;
    return v.f;
}

// ---------- fused CSR count + weight prep (merged dispatch, R7 version) ----------
constexpr int CB = (ETOT + 255) / 256;   // 2920
__global__ void count_prep(const int* __restrict__ dst0, const int* __restrict__ dst1,
                           const int* __restrict__ dst2, int* __restrict__ cnt,
                           const float* __restrict__ Wl0, const float* __restrict__ Wr0,
                           unsigned short* __restrict__ Wt0a, unsigned short* __restrict__ Wt0b,
                           const float* __restrict__ Wl1, const float* __restrict__ Wr1,
                           unsigned short* __restrict__ Wt1a, unsigned short* __restrict__ Wt1b) {
    int b = blockIdx.x, t = threadIdx.x;
    if (b < CB) {
        int i = b * 256 + t;
        if (i < E0) atomicAdd(&cnt[dst0[i]], 1);
        else if (i < E0 + E1) atomicAdd(&cnt[NN1 + dst1[i - E0]], 1);
        else if (i < ETOT) atomicAdd(&cnt[NN1 + NN2 + dst2[i - E0 - E1]], 1);
        return;
    }
    b -= CB;
    if (b < 128) {
        int idx = b * 256 + t; int n = idx >> 7, k = idx & 127;
        Wt0a[idx] = f2bf(k < 100 ? Wl0[k * 256 + n] : 0.f);
    } else if (b < 256) {
        int idx = (b - 128) * 256 + t; int n = idx >> 7, k = idx & 127;
        Wt0b[idx] = f2bf(k < 100 ? Wr0[k * 256 + n] : 0.f);
    } else if (b < 512) {
        int idx = (b - 256) * 256 + t; int n = idx >> 8, k = idx & 255;
        Wt1a[idx] = f2bf(Wl1[k * 256 + n]);
    } else {
        int idx = (b - 512) * 256 + t; int n = idx >> 8, k = idx & 255;
        Wt1b[idx] = f2bf(Wr1[k * 256 + n]);
    }
}

__global__ __launch_bounds__(1024) void scan1(const int* __restrict__ cnt, int n,
                                              int* __restrict__ ofs, int* __restrict__ sums) {
    __shared__ int s[1024];
    int i = blockIdx.x * 1024 + threadIdx.x;
    int v = (i < n) ? cnt[i] : 0;
    s[threadIdx.x] = v;
    __syncthreads();
    for (int off = 1; off < 1024; off <<= 1) {
        int t = (threadIdx.x >= off) ? s[threadIdx.x - off] : 0;
        __syncthreads();
        s[threadIdx.x] += t;
        __syncthreads();
    }
    if (i < n) ofs[i] = s[threadIdx.x] - v;
    if (threadIdx.x == 1023) sums[blockIdx.x] = s[1023];
}

__global__ void scan3(const int* __restrict__ sums, int n,
                      int* __restrict__ ofs, int* __restrict__ cursor) {
    __shared__ int pref_s;
    int c = (blockIdx.x * 256) >> 10;
    if (threadIdx.x < 64) {
        int v = 0;
        for (int j = threadIdx.x; j < c; j += 64) v += sums[j];
        for (int o = 32; o; o >>= 1) v += __shfl_down(v, o);
        if (threadIdx.x == 0) pref_s = v;
    }
    __syncthreads();
    int i = blockIdx.x * 256 + threadIdx.x;
    if (i < n) {
        int v = ofs[i] + pref_s;
        ofs[i] = v;
        cursor[i] = v;
    }
    if (blockIdx.x == 0 && threadIdx.x == 0) ofs[n] = ETOT;
}

__global__ void scatter_all(const int* __restrict__ src0, const int* __restrict__ dst0,
                            const int* __restrict__ src1, const int* __restrict__ dst1,
                            const int* __restrict__ src2, const int* __restrict__ dst2,
                            int* __restrict__ cursor, int* __restrict__ perm) {
    int i = blockIdx.x * 256 + threadIdx.x;
    if (i < E0) {
        int p = atomicAdd(&cursor[dst0[i]], 1);
        perm[p] = src0[i];
    } else if (i < E0 + E1) {
        int j = i - E0;
        int p = atomicAdd(&cursor[NN1 + dst1[j]], 1);
        perm[p] = src1[j];
    } else if (i < ETOT) {
        int j = i - E0 - E1;
        int p = atomicAdd(&cursor[NN1 + NN2 + dst2[j]], 1);
        perm[p] = src2[j];
    }
}

// ---------- fused layer 0 (R10 version): BM=64, pair-pipelined gather, Bs LDS staging ----------
__global__ __launch_bounds__(512) void fused_l0(const float* __restrict__ x,
                                                const int* __restrict__ perm,
                                                const int* __restrict__ ofs,
                                                const unsigned short* __restrict__ Wt0a,
                                                const unsigned short* __restrict__ Wt0b,
                                                const float* __restrict__ bias,
                                                unsigned short* __restrict__ h1) {
    __shared__ unsigned short As[64][136];
    __shared__ unsigned short Bs[256][40];
    int tid = threadIdx.x;
    int lane = tid & 63, wid = tid >> 6;
    int bm = blockIdx.x * 64;

    // ---- gather phase (pair-pipelined, 8 rows per wave) ----
    {
        int g = lane >> 5, l5 = lane & 31;
        bool act = l5 < 25;
        int node0 = bm + wid * 8;
        int myofs = (lane < 9) ? ofs[node0 + lane] : 0;

        int s0a = __shfl(myofs, 0);
        int s0b = __shfl(myofs, 1);
        int s1b = __shfl(myofs, 2);
        int dega = s0b - s0a, degb = s1b - s0b;
        int dca = min(dega, 64), dcb = min(degb, 64);
        int pea = (lane < dca) ? perm[s0a + lane] : 0;
        int peb = (lane < dcb) ? perm[s0b + lane] : 0;

        for (int r = 0; r < 8; r += 2) {
            int s0a_n = 0, s0b_n = 0, dega_n = 0, degb_n = 0, dca_n = 0, dcb_n = 0;
            int pea_n = 0, peb_n = 0;
            if (r + 2 < 8) {
                s0a_n = __shfl(myofs, r + 2);
                s0b_n = __shfl(myofs, r + 3);
                int s1b_n = __shfl(myofs, r + 4);
                dega_n = s0b_n - s0a_n; degb_n = s1b_n - s0b_n;
                dca_n = min(dega_n, 64); dcb_n = min(degb_n, 64);
                pea_n = (lane < dca_n) ? perm[s0a_n + lane] : 0;
                peb_n = (lane < dcb_n) ? perm[s0b_n + lane] : 0;
            }
            f32x4_t A0 = {0.f, 0.f, 0.f, 0.f}, A1 = A0, A2 = A0, A3 = A0;
            f32x4_t B0 = A0, B1 = A0, B2 = A0, B3 = A0;
            int mx = max(dca, dcb);
            for (int b = 0; b < mx; b += 8) {
                int e0 = b + g, e1 = b + 2 + g, e2 = b + 4 + g, e3 = b + 6 + g;
                int pa0 = __shfl(pea, e0), pa1 = __shfl(pea, e1);
                int pa2 = __shfl(pea, e2), pa3 = __shfl(pea, e3);
                int pb0 = __shfl(peb, e0), pb1 = __shfl(peb, e1);
                int pb2 = __shfl(peb, e2), pb3 = __shfl(peb, e3);
                f32x4_t z = {0.f, 0.f, 0.f, 0.f};
                f32x4_t va0 = z, va1 = z, va2 = z, va3 = z;
                f32x4_t vb0 = z, vb1 = z, vb2 = z, vb3 = z;
                if (act && e0 < dca) va0 = *reinterpret_cast<const f32x4_t*>(x + (size_t)pa0 * 100 + l5 * 4);
                if (act && e1 < dca) va1 = *reinterpret_cast<const f32x4_t*>(x + (size_t)pa1 * 100 + l5 * 4);
                if (act && e2 < dca) va2 = *reinterpret_cast<const f32x4_t*>(x + (size_t)pa2 * 100 + l5 * 4);
                if (act && e3 < dca) va3 = *reinterpret_cast<const f32x4_t*>(x + (size_t)pa3 * 100 + l5 * 4);
                if (act && e0 < dcb) vb0 = *reinterpret_cast<const f32x4_t*>(x + (size_t)pb0 * 100 + l5 * 4);
                if (act && e1 < dcb) vb1 = *reinterpret_cast<const f32x4_t*>(x + (size_t)pb1 * 100 + l5 * 4);
                if (act && e2 < dcb) vb2 = *reinterpret_cast<const f32x4_t*>(x + (size_t)pb2 * 100 + l5 * 4);
                if (act && e3 < dcb) vb3 = *reinterpret_cast<const f32x4_t*>(x + (size_t)pb3 * 100 + l5 * 4);
                A0 += va0; A1 += va1; A2 += va2; A3 += va3;
                B0 += vb0; B1 += vb1; B2 += vb2; B3 += vb3;
            }
            for (int e = s0a + 64; e < s0a + dega; e += 2) {
                int idx = e + g;
                if (act && idx < s0a + dega)
                    A0 += *reinterpret_cast<const f32x4_t*>(x + (size_t)perm[idx] * 100 + l5 * 4);
            }
            for (int e = s0b + 64; e < s0b + degb; e += 2) {
                int idx = e + g;
                if (act && idx < s0b + degb)
                    B0 += *reinterpret_cast<const f32x4_t*>(x + (size_t)perm[idx] * 100 + l5 * 4);
            }
            f32x4_t a = (A0 + A1) + (A2 + A3);
            f32x4_t bb = (B0 + B1) + (B2 + B3);
#pragma unroll
            for (int c = 0; c < 4; c++) {
                a[c] += __shfl_xor(a[c], 32);
                bb[c] += __shfl_xor(bb[c], 32);
            }
            float inva = 1.0f / fmaxf((float)dega, 1.0f);
            float invb = 1.0f / fmaxf((float)degb, 1.0f);
            int rowa = wid * 8 + r, rowb = rowa + 1;
            if (lane < 25) {
                ushort4 oa, ob;
                oa.x = f2bf(a[0] * inva); oa.y = f2bf(a[1] * inva);
                oa.z = f2bf(a[2] * inva); oa.w = f2bf(a[3] * inva);
                ob.x = f2bf(bb[0] * invb); ob.y = f2bf(bb[1] * invb);
                ob.z = f2bf(bb[2] * invb); ob.w = f2bf(bb[3] * invb);
                *reinterpret_cast<ushort4*>(&As[rowa][lane * 4]) = oa;
                *reinterpret_cast<ushort4*>(&As[rowb][lane * 4]) = ob;
            } else if (lane < 32) {
                ushort4 z4 = make_ushort4(0, 0, 0, 0);
                *reinterpret_cast<ushort4*>(&As[rowa][100 + (lane - 25) * 4]) = z4;
                *reinterpret_cast<ushort4*>(&As[rowb][100 + (lane - 25) * 4]) = z4;
            }
            s0a = s0a_n; s0b = s0b_n; dega = dega_n; degb = degb_n;
            dca = dca_n; dcb = dcb_n; pea = pea_n; peb = peb_n;
        }
    }

    f32x4_t acc[4][2];
#pragma unroll
    for (int i = 0; i < 4; i++)
#pragma unroll
        for (int j = 0; j < 2; j++)
#pragma unroll
            for (int r = 0; r < 4; r++) acc[i][j][r] = 0.f;

    int r0 = lane & 15, kg = lane >> 4;
    int wn = wid * 32;

    for (int pass = 0; pass < 2; ++pass) {
        const unsigned short* W = pass ? Wt0b : Wt0a;
        if (pass) {
            __syncthreads();
            for (int c = tid; c < 2048; c += 512) {
                int row = c >> 5, c4 = c & 31;
                if (c4 < 25) {
                    f32x4_t v = *reinterpret_cast<const f32x4_t*>(x + (size_t)(bm + row) * 100 + c4 * 4);
                    ushort4 o;
                    o.x = f2bf(v[0]); o.y = f2bf(v[1]); o.z = f2bf(v[2]); o.w = f2bf(v[3]);
                    *reinterpret_cast<ushort4*>(&As[row][c4 * 4]) = o;
                } else {
                    *reinterpret_cast<ushort4*>(&As[row][c4 * 4]) = make_ushort4(0, 0, 0, 0);
                }
            }
        }
#pragma unroll
        for (int ks = 0; ks < 4; ++ks) {
            __syncthreads();
            for (int c = tid; c < 1024; c += 512) {
                int n = c >> 2, k8 = (c & 3) << 3;
                *reinterpret_cast<int4*>(&Bs[n][k8]) =
                    *reinterpret_cast<const int4*>(&W[(size_t)n * 128 + ks * 32 + k8]);
            }
            __syncthreads();
            bf16x8_t af[4], bfv[2];
#pragma unroll
            for (int ni = 0; ni < 2; ni++)
                bfv[ni] = *reinterpret_cast<const bf16x8_t*>(&Bs[wn + ni * 16 + r0][kg * 8]);
#pragma unroll
            for (int mi = 0; mi < 4; mi++)
                af[mi] = *reinterpret_cast<const bf16x8_t*>(&As[mi * 16 + r0][ks * 32 + kg * 8]);
#pragma unroll
            for (int mi = 0; mi < 4; mi++)
#pragma unroll
                for (int ni = 0; ni < 2; ni++)
                    acc[mi][ni] = __builtin_amdgcn_mfma_f32_16x16x32_bf16(af[mi], bfv[ni], acc[mi][ni], 0, 0, 0);
        }
    }

    int cc = lane & 15, rr = (lane >> 4) * 4;
#pragma unroll
    for (int mi = 0; mi < 4; mi++) {
#pragma unroll
        for (int ni = 0; ni < 2; ni++) {
            int col = wn + ni * 16 + cc;
            float b = bias[col];
#pragma unroll
            for (int j = 0; j < 4; j++) {
                int row = bm + mi * 16 + rr + j;
                float v = fmaxf(acc[mi][ni][j] + b, 0.f);
                h1[(size_t)row * 256 + col] = f2bf(v);
            }
        }
    }
}

// ---------- fused layer 1 (R7 version): gather-mean(h1) + dual MFMA + ReLU -> h2 fp32 ----------
// Block: 64 dst rows x 128 cols, grid (2, 128), 512 threads (8 waves, 2M x 4N of 32x32).
__global__ __launch_bounds__(512) void fused_l1(const unsigned short* __restrict__ h1,
                                                const int* __restrict__ perm,
                                                const int* __restrict__ ofs,
                                                const unsigned short* __restrict__ Wt1a,
                                                const unsigned short* __restrict__ Wt1b,
                                                const float* __restrict__ bias,
                                                float* __restrict__ h2) {
    __shared__ unsigned short As[64][264];
    __shared__ unsigned short Bs[128][40];
    int tid = threadIdx.x;
    int lane = tid & 63, wid = tid >> 6;
    int bm = blockIdx.y * 64, bn = blockIdx.x * 128;

    {
        int node0 = bm + wid * 8;
        int myofs = (lane < 9) ? ofs[node0 + lane] : 0;
        for (int r = 0; r < 8; ++r) {
            int row = wid * 8 + r;
            int s0 = __shfl(myofs, r), s1 = __shfl(myofs, r + 1);
            int deg = s1 - s0;
            float inv = 1.0f / fmaxf((float)deg, 1.0f);
            int dcap = min(deg, 64);
            int pe = (lane < dcap) ? perm[s0 + lane] : 0;
            float ac[4][4] = {};
            for (int b = 0; b < dcap; b += 4) {
#pragma unroll
                for (int u = 0; u < 4; u++) {
                    int pu = __shfl(pe, b + u);
                    ushort4 v = make_ushort4(0, 0, 0, 0);
                    if (b + u < dcap)
                        v = *reinterpret_cast<const ushort4*>(h1 + (size_t)pu * 256 + lane * 4);
                    ac[u][0] += bf2f(v.x); ac[u][1] += bf2f(v.y);
                    ac[u][2] += bf2f(v.z); ac[u][3] += bf2f(v.w);
                }
            }
            for (int e = s0 + 64; e < s1; e++) {
                ushort4 v = *reinterpret_cast<const ushort4*>(h1 + (size_t)perm[e] * 256 + lane * 4);
                ac[0][0] += bf2f(v.x); ac[0][1] += bf2f(v.y);
                ac[0][2] += bf2f(v.z); ac[0][3] += bf2f(v.w);
            }
            ushort4 o;
            o.x = f2bf((ac[0][0] + ac[1][0] + ac[2][0] + ac[3][0]) * inv);
            o.y = f2bf((ac[0][1] + ac[1][1] + ac[2][1] + ac[3][1]) * inv);
            o.z = f2bf((ac[0][2] + ac[1][2] + ac[2][2] + ac[3][2]) * inv);
            o.w = f2bf((ac[0][3] + ac[1][3] + ac[2][3] + ac[3][3]) * inv);
            *reinterpret_cast<ushort4*>(&As[row][lane * 4]) = o;
        }
    }

    f32x4_t acc[2][2];
#pragma unroll
    for (int i = 0; i < 2; i++)
#pragma unroll
        for (int j = 0; j < 2; j++)
#pragma unroll
            for (int r = 0; r < 4; r++) acc[i][j][r] = 0.f;

    int r0 = lane & 15, kg = lane >> 4;
    int wm = (wid >> 2) * 32, wn = (wid & 3) * 32;

    for (int pass = 0; pass < 2; ++pass) {
        const unsigned short* W = pass ? Wt1b : Wt1a;
        if (pass) {
            __syncthreads();
            for (int c = tid; c < 2048; c += 512) {
                int row = c >> 5, k8 = (c & 31) << 3;
                *reinterpret_cast<int4*>(&As[row][k8]) =
                    *reinterpret_cast<const int4*>(&h1[(size_t)(bm + row) * 256 + k8]);
            }
        }
        for (int ks = 0; ks < 8; ++ks) {
            __syncthreads();
            {
                int c = tid;
                int n = c >> 2, k8 = (c & 3) << 3;
                *reinterpret_cast<int4*>(&Bs[n][k8]) =
                    *reinterpret_cast<const int4*>(&W[(size_t)(bn + n) * 256 + ks * 32 + k8]);
            }
            __syncthreads();
            bf16x8_t af[2], bfv[2];
#pragma unroll
            for (int mi = 0; mi < 2; mi++)
                af[mi] = *reinterpret_cast<const bf16x8_t*>(&As[wm + mi * 16 + r0][ks * 32 + kg * 8]);
#pragma unroll
            for (int ni = 0; ni < 2; ni++)
                bfv[ni] = *reinterpret_cast<const bf16x8_t*>(&Bs[wn + ni * 16 + r0][kg * 8]);
#pragma unroll
            for (int mi = 0; mi < 2; mi++)
#pragma unroll
                for (int ni = 0; ni < 2; ni++)
                    acc[mi][ni] = __builtin_amdgcn_mfma_f32_16x16x32_bf16(af[mi], bfv[ni], acc[mi][ni], 0, 0, 0);
        }
    }

    int cc = lane & 15, rr = (lane >> 4) * 4;
#pragma unroll
    for (int mi = 0; mi < 2; mi++) {
#pragma unroll
        for (int ni = 0; ni < 2; ni++) {
            int col = bn + wn + ni * 16 + cc;
            float b = bias[col];
#pragma unroll
            for (int j = 0; j < 4; j++) {
                int row = bm + wm + mi * 16 + rr + j;
                h2[(size_t)row * 256 + col] = fmaxf(acc[mi][ni][j] + b, 0.f);
            }
        }
    }
}

// ---------- layer 2 all-in-one (R7 version): gather in LDS + fp32 dual GEMM + log_softmax ----------
__global__ __launch_bounds__(256) void gemm2_all(const float* __restrict__ h2,
                                                 const int* __restrict__ perm,
                                                 const int* __restrict__ ofs,
                                                 const float* __restrict__ W1,
                                                 const float* __restrict__ W2,
                                                 const float* __restrict__ bias,
                                                 float* __restrict__ out,
                                                 int M, int N) {
    __shared__ float Agg[64][260];
    __shared__ float As[16][65];
    __shared__ float Bs[16][64];
    int tid = threadIdx.x;
    int lane = tid & 63, wid = tid >> 6;
    int bm = blockIdx.y * 64;

    {
        int node0 = bm + wid * 16;
        int myofs = (lane < 17) ? ofs[node0 + lane] : 0;
        for (int r = 0; r < 16; ++r) {
            int row = wid * 16 + r;
            int s0 = __shfl(myofs, r), s1 = __shfl(myofs, r + 1);
            int deg = s1 - s0;
            float inv = 1.0f / fmaxf((float)deg, 1.0f);
            int dcap = min(deg, 64);
            int pe = (lane < dcap) ? perm[s0 + lane] : 0;
            f32x4_t B0 = {0.f, 0.f, 0.f, 0.f}, B1 = B0, B2 = B0, B3 = B0;
            for (int b = 0; b < dcap; b += 4) {
                int p0 = __shfl(pe, b), p1 = __shfl(pe, b + 1);
                int p2 = __shfl(pe, b + 2), p3 = __shfl(pe, b + 3);
                f32x4_t v0 = {0.f, 0.f, 0.f, 0.f}, v1 = v0, v2 = v0, v3 = v0;
                if (b < dcap)     v0 = *reinterpret_cast<const f32x4_t*>(h2 + (size_t)p0 * 256 + lane * 4);
                if (b + 1 < dcap) v1 = *reinterpret_cast<const f32x4_t*>(h2 + (size_t)p1 * 256 + lane * 4);
                if (b + 2 < dcap) v2 = *reinterpret_cast<const f32x4_t*>(h2 + (size_t)p2 * 256 + lane * 4);
                if (b + 3 < dcap) v3 = *reinterpret_cast<const f32x4_t*>(h2 + (size_t)p3 * 256 + lane * 4);
                B0 += v0; B1 += v1; B2 += v2; B3 += v3;
            }
            for (int e = s0 + 64; e < s1; e++)
                B0 += *reinterpret_cast<const f32x4_t*>(h2 + (size_t)perm[e] * 256 + lane * 4);
            f32x4_t a = (B0 + B1) + (B2 + B3);
#pragma unroll
            for (int c = 0; c < 4; c++) Agg[row][lane * 4 + c] = a[c] * inv;
        }
    }
    __syncthreads();

    int tx = tid & 15, ty = tid >> 4;
    float acc[4][4] = {};
    for (int pass = 0; pass < 2; ++pass) {
        const float* W = pass ? W2 : W1;
        for (int k0 = 0; k0 < 256; k0 += 16) {
            __syncthreads();
#pragma unroll
            for (int i = 0; i < 4; i++) {
                int L = i * 256 + tid;
                int m = L >> 4, k = L & 15;
                As[k][m] = pass ? h2[(size_t)(bm + m) * 256 + k0 + k] : Agg[m][k0 + k];
            }
#pragma unroll
            for (int i = 0; i < 4; i++) {
                int L = i * 256 + tid;
                int n = L & 63, k = L >> 6;
                float v = 0.f;
                if (n < N) v = W[(size_t)(k0 + k) * N + n];
                Bs[k][n] = v;
            }
            __syncthreads();
#pragma unroll
            for (int k = 0; k < 16; k++) {
                float a[4], b[4];
#pragma unroll
                for (int i = 0; i < 4; i++) a[i] = As[k][ty * 4 + i];
#pragma unroll
                for (int j = 0; j < 4; j++) b[j] = Bs[k][tx * 4 + j];
#pragma unroll
                for (int i = 0; i < 4; i++)
#pragma unroll
                    for (int j = 0; j < 4; j++) acc[i][j] += a[i] * b[j];
            }
        }
    }
#pragma unroll
    for (int i = 0; i < 4; i++) {
        int gm = bm + ty * 4 + i;
        float vals[4];
        float vmax = -1e30f;
#pragma unroll
        for (int j = 0; j < 4; j++) {
            int gn = tx * 4 + j;
            vals[j] = (gn < N) ? acc[i][j] + bias[gn] : -1e30f;
            vmax = fmaxf(vmax, vals[j]);
        }
#pragma unroll
        for (int o = 1; o < 16; o <<= 1) vmax = fmaxf(vmax, __shfl_xor(vmax, o));
        float se = 0.f;
#pragma unroll
        for (int j = 0; j < 4; j++) {
            int gn = tx * 4 + j;
            if (gn < N) se += expf(vals[j] - vmax);
        }
#pragma unroll
        for (int o = 1; o < 16; o <<= 1) se += __shfl_xor(se, o);
        float ls = logf(se);
#pragma unroll
        for (int j = 0; j < 4; j++) {
            int gn = tx * 4 + j;
            if (gn < N && gm < M) out[(size_t)gm * N + gn] = vals[j] - vmax - ls;
        }
    }
}

extern "C" void kernel_launch(void* const* d_in, const int* in_sizes, int n_in,
                              void* d_out, int out_size, void* d_ws, size_t ws_size,
                              hipStream_t stream) {
    const float* x   = (const float*)d_in[0];
    const int* src0  = (const int*)d_in[1];
    const int* dst0  = (const int*)d_in[2];
    const int* src1  = (const int*)d_in[3];
    const int* dst1  = (const int*)d_in[4];
    const int* src2  = (const int*)d_in[5];
    const int* dst2  = (const int*)d_in[6];
    const float* Wl0 = (const float*)d_in[7];
    const float* bl0 = (const float*)d_in[8];
    const float* Wr0 = (const float*)d_in[9];
    const float* Wl1 = (const float*)d_in[10];
    const float* bl1 = (const float*)d_in[11];
    const float* Wr1 = (const float*)d_in[12];
    const float* Wl2 = (const float*)d_in[13];
    const float* bl2 = (const float*)d_in[14];
    const float* Wr2 = (const float*)d_in[15];
    float* out = (float*)d_out;

    // ---- workspace layout ----
    char* p = (char*)d_ws;
    auto alloc = [&](size_t bytes) { char* r = p; p += (bytes + 255) & ~(size_t)255; return r; };
    unsigned short* h1   = (unsigned short*)alloc((size_t)NN1 * 256 * 2);
    float* h2    = (float*)alloc((size_t)NN2 * 256 * 4);
    unsigned short* Wt0a = (unsigned short*)alloc(256 * 128 * 2);
    unsigned short* Wt0b = (unsigned short*)alloc(256 * 128 * 2);
    unsigned short* Wt1a = (unsigned short*)alloc(256 * 256 * 2);
    unsigned short* Wt1b = (unsigned short*)alloc(256 * 256 * 2);
    int* cnt    = (int*)alloc((size_t)NTOT * 4);
    int* ofs    = (int*)alloc((size_t)(NTOT + 1) * 4);
    int* cursor = (int*)alloc((size_t)(NTOT + 1) * 4);
    int* sums   = (int*)alloc(128 * 4);
    int* perm   = (int*)alloc((size_t)ETOT * 4);

    // ---- CSR build + weight prep ----
    hipMemsetAsync(cnt, 0, (size_t)NTOT * 4, stream);
    count_prep<<<CB + 768, 256, 0, stream>>>(dst0, dst1, dst2, cnt,
                                             Wl0, Wr0, Wt0a, Wt0b, Wl1, Wr1, Wt1a, Wt1b);
    int nb = cdiv(NTOT, 1024);   // 73
    scan1<<<nb, 1024, 0, stream>>>(cnt, NTOT, ofs, sums);
    scan3<<<cdiv(NTOT, 256), 256, 0, stream>>>(sums, NTOT, ofs, cursor);
    scatter_all<<<cdiv(ETOT, 256), 256, 0, stream>>>(src0, dst0, src1, dst1, src2, dst2, cursor, perm);

    // ---- layer 0 (BM=64, pair-pipelined gather, Bs staged) ----
    fused_l0<<<NN1 / 64, 512, 0, stream>>>(x, perm, ofs, Wt0a, Wt0b, bl0, h1);

    // ---- layer 1 (R7 structure) ----
    {
        dim3 grid(2, NN2 / 64);
        fused_l1<<<grid, 512, 0, stream>>>(h1, perm, ofs + NN1, Wt1a, Wt1b, bl1, h2);
    }

    // ---- layer 2 (R7 merged gather + GEMM + log_softmax) ----
    {
        dim3 grid(1, NN3 / 64);
        gemm2_all<<<grid, 256, 0, stream>>>(h2, perm, ofs + NN1 + NN2, Wl2, Wr2, bl2, out, NN3, 47);
    }
}